// Round 4
// baseline (416.512 us; speedup 1.0000x reference)
//
#include <hip/hip_runtime.h>
#include <math.h>

#define M 16
#define KD 1024
#define CS_EPS 1e-6f

#define N0 (1024 * 1024)          // elements in rec0
#define N1 (1024 * 4096)          // elements in rec1
#define N40 (N0 / 4)              // float4 count, V0 slot  = 262144
#define N41 (N1 / 4)              // float4 count, V1 slot  = 1048576

typedef float vf4 __attribute__((ext_vector_type(4)));   // native vec for NT builtins

// ---------------------------------------------------------------------------
// Kernel 1: cosine similarity of task_emb vs each of M keys, softmax -> w[M]
// ---------------------------------------------------------------------------
__global__ __launch_bounds__(1024) void addr_head_kernel(
    const float* __restrict__ task_emb,   // [KD]
    const float* __restrict__ K_memory,   // [M, KD]
    float* __restrict__ w_out)            // [M]
{
    __shared__ float s_cos[M];
    const int lane = threadIdx.x & 63;
    const int wave = threadIdx.x >> 6;    // 0..15 == slot index

    float dot = 0.f, n2sq = 0.f, n1sq = 0.f;
#pragma unroll
    for (int k = 0; k < KD / 64; ++k) {
        float t  = task_emb[lane + k * 64];
        float km = K_memory[wave * KD + lane + k * 64];
        dot  += t * km;
        n2sq += km * km;
        n1sq += t * t;
    }
#pragma unroll
    for (int off = 32; off; off >>= 1) {
        dot  += __shfl_down(dot,  off, 64);
        n2sq += __shfl_down(n2sq, off, 64);
        n1sq += __shfl_down(n1sq, off, 64);
    }
    if (lane == 0) {
        float denom = fmaxf(sqrtf(n1sq) * sqrtf(n2sq), CS_EPS);
        s_cos[wave] = dot / denom;
    }
    __syncthreads();
    if (threadIdx.x == 0) {
        float mx = -1e30f;
#pragma unroll
        for (int m = 0; m < M; ++m) mx = fmaxf(mx, s_cos[m]);
        float e[M];
        float sum = 0.f;
#pragma unroll
        for (int m = 0; m < M; ++m) { e[m] = expf(s_cos[m] - mx); sum += e[m]; }
        float inv = 1.f / sum;
#pragma unroll
        for (int m = 0; m < M; ++m) w_out[m] = e[m] * inv;
    }
}

// ---------------------------------------------------------------------------
// Kernel 2: out[i] = sum_m w[m] * V[m][i]
//   - PITCH4 compile-time -> slot bases are SGPR constants
//   - 2 float4 outputs per thread -> 2560 blocks = 10240 waves (fills all
//     8192 wave slots; smooth drain). 32 plain loads per thread.
//   - weights broadcast to SGPRs via readfirstlane
//   - plain loads (keep L3 hits from harness-restored inputs); NT stores only
// ---------------------------------------------------------------------------
__device__ __forceinline__ float sgpr_bcast(float x) {
    return __int_as_float(__builtin_amdgcn_readfirstlane(__float_as_int(x)));
}

template<int PITCH4>
__device__ __forceinline__ void wsum_body(
    const vf4* __restrict__ V,
    const float* __restrict__ w,
    vf4* __restrict__ out,
    int blk)
{
    const long long base = (long long)blk * 512 + threadIdx.x;

    float ws[M];
#pragma unroll
    for (int m = 0; m < M; ++m) ws[m] = sgpr_bcast(w[m]);

    vf4 acc0 = (vf4)(0.f);
    vf4 acc1 = (vf4)(0.f);

#pragma unroll
    for (int m = 0; m < M; ++m) {
        const vf4* __restrict__ p = V + (long long)m * PITCH4 + base;
        vf4 a = p[0];
        vf4 b = p[256];
        acc0.x = fmaf(ws[m], a.x, acc0.x);
        acc0.y = fmaf(ws[m], a.y, acc0.y);
        acc0.z = fmaf(ws[m], a.z, acc0.z);
        acc0.w = fmaf(ws[m], a.w, acc0.w);
        acc1.x = fmaf(ws[m], b.x, acc1.x);
        acc1.y = fmaf(ws[m], b.y, acc1.y);
        acc1.z = fmaf(ws[m], b.z, acc1.z);
        acc1.w = fmaf(ws[m], b.w, acc1.w);
    }
    __builtin_nontemporal_store(acc0, &out[base]);
    __builtin_nontemporal_store(acc1, &out[base + 256]);
}

__global__ __launch_bounds__(256) void wsum_kernel(
    const vf4* __restrict__ V0,
    const vf4* __restrict__ V1,
    const float* __restrict__ w,
    vf4* __restrict__ out)
{
    const int b = blockIdx.x;
    if (b < N40 / 512) {                        // 512 blocks -> V0
        wsum_body<N40>(V0, w, out, b);
    } else {                                    // 2048 blocks -> V1
        wsum_body<N41>(V1, w, out + N40, b - N40 / 512);
    }
}

extern "C" void kernel_launch(void* const* d_in, const int* in_sizes, int n_in,
                              void* d_out, int out_size, void* d_ws, size_t ws_size,
                              hipStream_t stream) {
    const float* task_emb = (const float*)d_in[0];   // [1,1024]
    const float* K_memory = (const float*)d_in[1];   // [16,1024]
    const float* V0       = (const float*)d_in[2];   // [16,1024,1024]
    const float* V1       = (const float*)d_in[3];   // [16,1024,4096]
    float* w   = (float*)d_ws;                       // 16 floats scratch
    float* out = (float*)d_out;                      // [N0 + N1]

    addr_head_kernel<<<1, 1024, 0, stream>>>(task_emb, K_memory, w);

    const int nblk = (N40 + N41) / 512;              // 2560 blocks
    wsum_kernel<<<nblk, 256, 0, stream>>>(
        (const vf4*)V0, (const vf4*)V1, w, (vf4*)out);
}